// Round 1
// baseline (798.077 us; speedup 1.0000x reference)
//
#include <hip/hip_runtime.h>

// ---------------------------------------------------------------------------
// QuantizedAttention: x[B,S,D] -> QKV proj (int8-quant wts) -> RMSNorm -> RoPE
//   -> causal GQA attention -> O proj.  B=2 S=2048 D=2048 H=16 KVH=8 HD=128.
// Strategy: bf16 MFMA GEMMs (weights exact in bf16, scales applied fp32 in
// epilogue), flash-style attention with online softmax.
// Host float-storage dtype (fp32 vs packed bf16) detected on-device.
// ---------------------------------------------------------------------------

typedef __attribute__((ext_vector_type(4))) float floatx4;
typedef __attribute__((ext_vector_type(8))) short short8v;
typedef __attribute__((ext_vector_type(8))) unsigned short ushort8v;
typedef __attribute__((ext_vector_type(4))) unsigned short ushort4v;

#define DEVINL __device__ __forceinline__

constexpr int cB = 2, cS = 2048, cD = 2048, cH = 16, cKVH = 8, cHD = 128;
constexpr int cM = cB * cS;                      // 4096 token rows
constexpr int cNqkv = (cH + 2 * cKVH) * cHD;     // 4096 fused QKV out features
constexpr float cEPS = 1e-6f;
constexpr float cSCALE = 0.08838834764831845f;   // 1/sqrt(HD)

DEVINL unsigned short f2bf(float f) {            // RNE f32 -> bf16
  unsigned u = __float_as_uint(f);
  unsigned r = ((u >> 16) & 1u) + 0x7FFFu;
  return (unsigned short)((u + r) >> 16);
}
DEVINL float bf2f(unsigned short h) { return __uint_as_float(((unsigned)h) << 16); }

DEVINL floatx4 mfma_bf16(short8v a, short8v b, floatx4 c) {
  return __builtin_amdgcn_mfma_f32_16x16x32_bf16(a, b, c, 0, 0, 0);
}

// --------------------------- dtype detection -------------------------------
// If host stores floats as packed bf16, the low ushort of each 32-bit word is
// a bf16 of ~N(0,1): exponent field in [100,142] ~99.9% of the time. If fp32,
// those bits are mantissa noise: ~17% in window. Threshold at 60%.
__global__ void detect_dtype(const unsigned* __restrict__ x, int* __restrict__ flag) {
  __shared__ int cnt;
  if (threadIdx.x == 0) cnt = 0;
  __syncthreads();
  int c = 0;
  for (int i = threadIdx.x; i < 4096; i += 256) {
    unsigned e = (x[i] >> 7) & 0xFFu;
    c += (e >= 100u && e <= 142u) ? 1 : 0;
  }
  atomicAdd(&cnt, c);
  __syncthreads();
  if (threadIdx.x == 0) *flag = (cnt > 2457) ? 1 : 0;  // 1 = host is bf16
}

// --------------------------- conversions -----------------------------------
__global__ void conv_x(const void* __restrict__ src, unsigned short* __restrict__ dst,
                       int n, const int* __restrict__ flag) {
  int i = (blockIdx.x * 256 + threadIdx.x) * 8;
  if (i >= n) return;
  if (*flag) {
    *(ushort8v*)(dst + i) = *(const ushort8v*)((const unsigned short*)src + i);
  } else {
    const float* s = (const float*)src;
    ushort8v o;
#pragma unroll
    for (int j = 0; j < 8; j++) o[j] = f2bf(s[i + j]);
    *(ushort8v*)(dst + i) = o;
  }
}

__global__ void conv_f32(const void* __restrict__ src, float* __restrict__ dst,
                         int n, const int* __restrict__ flag) {
  int i = blockIdx.x * 256 + threadIdx.x;
  if (i >= n) return;
  dst[i] = (*flag) ? bf2f(((const unsigned short*)src)[i]) : ((const float*)src)[i];
}

__global__ void conv_w(const int* __restrict__ w, unsigned short* __restrict__ dst, int n) {
  int i = (blockIdx.x * 256 + threadIdx.x) * 4;
  if (i >= n) return;
  int4 v = *(const int4*)(w + i);
  ushort4v o;
  o[0] = f2bf((float)v.x); o[1] = f2bf((float)v.y);
  o[2] = f2bf((float)v.z); o[3] = f2bf((float)v.w);
  *(ushort4v*)(dst + i) = o;
}

__global__ void out_conv(const float* __restrict__ of, void* __restrict__ dout,
                         int n, const int* __restrict__ flag) {
  int i = blockIdx.x * 256 + threadIdx.x;
  if (i >= n) return;
  float v = of[i];
  if (*flag) ((unsigned short*)dout)[i] = f2bf(v);
  else       ((float*)dout)[i] = v;
}

// --------------------------- bf16 GEMM (B^T) -------------------------------
// C[M,N] = (A[M,K] @ B[N,K]^T) * colscale[N].  128x128x64 tiles, 4 waves,
// each wave 64x64 via 4x4 grid of 16x16x32 MFMA tiles. LDS padded +8 bf16.
__global__ __launch_bounds__(256) void gemm_bt(
    const unsigned short* __restrict__ A, const unsigned short* __restrict__ Bw,
    const float* __restrict__ colscale, float* __restrict__ C,
    int M, int N, int K) {
  constexpr int BK = 64, LDT = BK + 8;
  __shared__ unsigned short As[128 * LDT];
  __shared__ unsigned short Bs[128 * LDT];
  const int tid = threadIdx.x;
  const int lane = tid & 63, wave = tid >> 6;
  const int q = lane >> 4, l16 = lane & 15;
  const int m0 = blockIdx.y * 128, n0 = blockIdx.x * 128;
  const int wm = (wave & 1) * 64, wn = (wave >> 1) * 64;

  floatx4 acc[4][4] = {};

  const int srow = tid >> 1, scol = (tid & 1) * 32;
  const unsigned short* Ag = A + (size_t)(m0 + srow) * K + scol;
  const unsigned short* Bg = Bw + (size_t)(n0 + srow) * K + scol;
  unsigned short* Asw = As + srow * LDT + scol;
  unsigned short* Bsw = Bs + srow * LDT + scol;

  for (int k0 = 0; k0 < K; k0 += BK) {
    ushort8v a0 = *(const ushort8v*)(Ag + k0 + 0);
    ushort8v a1 = *(const ushort8v*)(Ag + k0 + 8);
    ushort8v a2 = *(const ushort8v*)(Ag + k0 + 16);
    ushort8v a3 = *(const ushort8v*)(Ag + k0 + 24);
    ushort8v b0 = *(const ushort8v*)(Bg + k0 + 0);
    ushort8v b1 = *(const ushort8v*)(Bg + k0 + 8);
    ushort8v b2 = *(const ushort8v*)(Bg + k0 + 16);
    ushort8v b3 = *(const ushort8v*)(Bg + k0 + 24);
    __syncthreads();
    *(ushort8v*)(Asw + 0)  = a0;
    *(ushort8v*)(Asw + 8)  = a1;
    *(ushort8v*)(Asw + 16) = a2;
    *(ushort8v*)(Asw + 24) = a3;
    *(ushort8v*)(Bsw + 0)  = b0;
    *(ushort8v*)(Bsw + 8)  = b1;
    *(ushort8v*)(Bsw + 16) = b2;
    *(ushort8v*)(Bsw + 24) = b3;
    __syncthreads();
#pragma unroll
    for (int kk = 0; kk < BK; kk += 32) {
      short8v af[4], bf[4];
#pragma unroll
      for (int mt = 0; mt < 4; mt++)
        af[mt] = *(const short8v*)(As + (wm + mt * 16 + l16) * LDT + kk + q * 8);
#pragma unroll
      for (int nt = 0; nt < 4; nt++)
        bf[nt] = *(const short8v*)(Bs + (wn + nt * 16 + l16) * LDT + kk + q * 8);
#pragma unroll
      for (int mt = 0; mt < 4; mt++)
#pragma unroll
        for (int nt = 0; nt < 4; nt++)
          acc[mt][nt] = mfma_bf16(af[mt], bf[nt], acc[mt][nt]);
    }
  }
#pragma unroll
  for (int mt = 0; mt < 4; mt++) {
    int r0 = m0 + wm + mt * 16 + q * 4;
#pragma unroll
    for (int nt = 0; nt < 4; nt++) {
      int cn = n0 + wn + nt * 16 + l16;
      float sc = colscale[cn];
#pragma unroll
      for (int rg = 0; rg < 4; rg++)
        C[(size_t)(r0 + rg) * N + cn] = acc[mt][nt][rg] * sc;
    }
  }
}

// --------------------------- RMSNorm + RoPE --------------------------------
// One 64-thread block per (token row, head). Reads fp32 fused-QKV GEMM out,
// writes bf16 Q[B,H,S,HD] / K[B,KVH,S,HD].
__global__ __launch_bounds__(64) void rmsrope(
    const float* __restrict__ QKV, const float* __restrict__ cosc,
    const float* __restrict__ sinc, const float* __restrict__ nw,
    unsigned short* __restrict__ Qb, unsigned short* __restrict__ Kb) {
  const int t = threadIdx.x;
  const int row = blockIdx.x;       // b*S + s
  const int hidx = blockIdx.y;      // 0..H+KVH-1
  const int sidx = row & (cS - 1);
  const int bi = row >> 11;
  const bool isq = hidx < cH;
  const int col = isq ? hidx * cHD : cH * cHD + (hidx - cH) * cHD;
  const float* src = QKV + (size_t)row * cNqkv + col;
  float x1 = src[t], x2 = src[t + 64];
  float ss = x1 * x1 + x2 * x2;
  ss += __shfl_xor(ss, 1);  ss += __shfl_xor(ss, 2);  ss += __shfl_xor(ss, 4);
  ss += __shfl_xor(ss, 8);  ss += __shfl_xor(ss, 16); ss += __shfl_xor(ss, 32);
  float inv = rsqrtf(ss * (1.0f / cHD) + cEPS);
  const float* w = nw + (isq ? 0 : cHD);
  float n1 = x1 * inv * w[t], n2 = x2 * inv * w[t + 64];
  float c1 = cosc[sidx * cHD + t], c2 = cosc[sidx * cHD + t + 64];
  float s1 = sinc[sidx * cHD + t], s2 = sinc[sidx * cHD + t + 64];
  float o1 = n1 * c1 - n2 * s1;   // rotate_half: [x1,x2] -> [-x2, x1]
  float o2 = n2 * c2 + n1 * s2;
  unsigned short* dst = isq
      ? (Qb + ((size_t)(bi * cH + hidx) * cS + sidx) * cHD)
      : (Kb + ((size_t)(bi * cKVH + (hidx - cH)) * cS + sidx) * cHD);
  dst[t] = f2bf(o1);
  dst[t + 64] = f2bf(o2);
}

// --------------------------- V transpose -----------------------------------
// fp32 QKV cols [3072,4096) -> bf16 Vt[B,KVH,HD,S] (so PV B-fragments read
// 16B contiguous along kv).
__global__ __launch_bounds__(256) void vtrans(const float* __restrict__ QKV,
                                              unsigned short* __restrict__ Vt) {
  __shared__ unsigned short tile[64][72];
  const int t = threadIdx.x;
  const int s0 = blockIdx.x * 64, d0 = blockIdx.y * 64, bi = blockIdx.z;
  {
    const int rr = t >> 2, c0 = (t & 3) * 16;
    const float* src = QKV + (size_t)(bi * cS + s0 + rr) * cNqkv
                       + (cH * cHD + cKVH * cHD) + d0 + c0;
#pragma unroll
    for (int j = 0; j < 16; j += 4) {
      float4 v = *(const float4*)(src + j);
      tile[rr][c0 + j + 0] = f2bf(v.x);
      tile[rr][c0 + j + 1] = f2bf(v.y);
      tile[rr][c0 + j + 2] = f2bf(v.z);
      tile[rr][c0 + j + 3] = f2bf(v.w);
    }
  }
  __syncthreads();
  {
    const int dd = t >> 2, sc0 = (t & 3) * 16;
    const int dglob = d0 + dd;
    const int kh = dglob >> 7, dh = dglob & 127;
    unsigned short* dst = Vt + ((size_t)(bi * cKVH + kh) * cHD + dh) * cS + s0 + sc0;
    ushort8v o0, o1;
#pragma unroll
    for (int j = 0; j < 8; j++) { o0[j] = tile[sc0 + j][dd]; o1[j] = tile[sc0 + 8 + j][dd]; }
    *(ushort8v*)dst = o0;
    *(ushort8v*)(dst + 8) = o1;
  }
}

// --------------------------- flash attention -------------------------------
// Block = (64 q-rows, head, batch); 4 waves, one wave per 16 q-rows.
// Per iter: 32 kv cols -> 8 QK^T MFMAs, online softmax (stats replicated
// across the 16 lanes of each quad), P through wave-private LDS (C-layout ->
// A-layout), 8 PV MFMAs. Causal mask exact per element.
__global__ __launch_bounds__(256) void attn(
    const unsigned short* __restrict__ Qb, const unsigned short* __restrict__ Kb,
    const unsigned short* __restrict__ Vt, unsigned short* __restrict__ AO) {
  __shared__ unsigned short Pl[4][16 * 40];
  const int tid = threadIdx.x;
  const int lane = tid & 63, wv = tid >> 6;
  const int q = lane >> 4, l16 = lane & 15;
  const int bi = blockIdx.z, h = blockIdx.y;
  const int kh = h >> 1;                      // rep = H/KVH = 2
  const int q0 = blockIdx.x * 64 + wv * 16;   // this wave's first q row

  const unsigned short* Qbase = Qb + ((size_t)(bi * cH + h) * cS + q0) * cHD;
  const unsigned short* Kbase = Kb + ((size_t)(bi * cKVH + kh) * cS) * cHD;
  const unsigned short* Vbase = Vt + ((size_t)(bi * cKVH + kh) * cHD) * cS;

  short8v qa[4];
#pragma unroll
  for (int c = 0; c < 4; c++)
    qa[c] = *(const short8v*)(Qbase + (size_t)l16 * cHD + c * 32 + q * 8);

  floatx4 oacc[8] = {};
  float m_r[4] = {-INFINITY, -INFINITY, -INFINITY, -INFINITY};
  float l_r[4] = {0.f, 0.f, 0.f, 0.f};

  const int kvmax = q0 + 16;
  for (int kv0 = 0; kv0 < kvmax; kv0 += 32) {
    floatx4 s0 = {}, s1 = {};
#pragma unroll
    for (int c = 0; c < 4; c++) {
      short8v k0 = *(const short8v*)(Kbase + (size_t)(kv0 + l16) * cHD + c * 32 + q * 8);
      short8v k1 = *(const short8v*)(Kbase + (size_t)(kv0 + 16 + l16) * cHD + c * 32 + q * 8);
      s0 = mfma_bf16(qa[c], k0, s0);
      s1 = mfma_bf16(qa[c], k1, s1);
    }
    float pm[2][4];
#pragma unroll
    for (int rg = 0; rg < 4; rg++) {
      int row = q0 + q * 4 + rg;
      pm[0][rg] = (kv0 + l16 <= row)      ? s0[rg] * cSCALE : -INFINITY;
      pm[1][rg] = (kv0 + 16 + l16 <= row) ? s1[rg] * cSCALE : -INFINITY;
    }
    float alpha[4];
#pragma unroll
    for (int rg = 0; rg < 4; rg++) {
      float mx = fmaxf(pm[0][rg], pm[1][rg]);
      mx = fmaxf(mx, __shfl_xor(mx, 1));
      mx = fmaxf(mx, __shfl_xor(mx, 2));
      mx = fmaxf(mx, __shfl_xor(mx, 4));
      mx = fmaxf(mx, __shfl_xor(mx, 8));
      float mnew = fmaxf(m_r[rg], mx);
      float a = __expf(m_r[rg] - mnew);     // first iter: exp(-inf)=0
      float p0 = __expf(pm[0][rg] - mnew);
      float p1 = __expf(pm[1][rg] - mnew);
      pm[0][rg] = p0; pm[1][rg] = p1;
      float ps = p0 + p1;
      ps += __shfl_xor(ps, 1);
      ps += __shfl_xor(ps, 2);
      ps += __shfl_xor(ps, 4);
      ps += __shfl_xor(ps, 8);
      l_r[rg] = l_r[rg] * a + ps;
      m_r[rg] = mnew;
      alpha[rg] = a;
    }
#pragma unroll
    for (int db = 0; db < 8; db++) {
      floatx4 o = oacc[db];
      o[0] *= alpha[0]; o[1] *= alpha[1]; o[2] *= alpha[2]; o[3] *= alpha[3];
      oacc[db] = o;
    }
    // P: C-layout (row=q*4+rg, col=t*16+l16) -> LDS -> A-layout read.
    // Same-wave LDS ops are processed in order; no barrier needed (wave-private).
    unsigned short* pw = &Pl[wv][0];
#pragma unroll
    for (int rg = 0; rg < 4; rg++) {
      pw[(q * 4 + rg) * 40 + l16]      = f2bf(pm[0][rg]);
      pw[(q * 4 + rg) * 40 + 16 + l16] = f2bf(pm[1][rg]);
    }
    short8v pa = *(const short8v*)(pw + l16 * 40 + q * 8);
#pragma unroll
    for (int db = 0; db < 8; db++) {
      short8v vb = *(const short8v*)(Vbase + (size_t)(db * 16 + l16) * cS + kv0 + q * 8);
      oacc[db] = mfma_bf16(pa, vb, oacc[db]);
    }
  }
#pragma unroll
  for (int rg = 0; rg < 4; rg++) {
    float inv = 1.0f / l_r[rg];
    int row = q0 + q * 4 + rg;
    unsigned short* dst = AO + (size_t)(bi * cS + row) * (cH * cHD) + h * cHD;
#pragma unroll
    for (int db = 0; db < 8; db++)
      dst[db * 16 + l16] = f2bf(oacc[db][rg] * inv);
  }
}

// --------------------------- launch ----------------------------------------
extern "C" void kernel_launch(void* const* d_in, const int* in_sizes, int n_in,
                              void* d_out, int out_size, void* d_ws, size_t ws_size,
                              hipStream_t stream) {
  (void)in_sizes; (void)n_in; (void)out_size; (void)ws_size;
  char* ws = (char*)d_ws;
  size_t off = 0;
  auto alloc = [&](size_t bytes) -> char* {
    char* p = ws + off;
    off += (bytes + 255) & ~((size_t)255);
    return p;
  };
  int* flag            = (int*)alloc(256);
  float* cosf_         = (float*)alloc((size_t)cS * cHD * 4);
  float* sinf_         = (float*)alloc((size_t)cS * cHD * 4);
  float* nw            = (float*)alloc(256 * 4);               // qw[0:128], kw[128:256]
  float* scat          = (float*)alloc(4096 * 4);              // wq_s|wk_s|wv_s
  float* so            = (float*)alloc(2048 * 4);
  unsigned short* xb   = (unsigned short*)alloc((size_t)cM * cD * 2);
  unsigned short* wcat = (unsigned short*)alloc((size_t)cNqkv * cD * 2);
  unsigned short* wob  = (unsigned short*)alloc((size_t)cD * cH * cHD * 2);
  unsigned short* Qb   = (unsigned short*)alloc((size_t)cB * cH * cS * cHD * 2);
  unsigned short* Kb   = (unsigned short*)alloc((size_t)cB * cKVH * cS * cHD * 2);
  unsigned short* Vt   = (unsigned short*)alloc((size_t)cB * cKVH * cHD * cS * 2);
  char* big            = alloc((size_t)cM * cNqkv * 4);        // 67MB, reused
  float* qkvf          = (float*)big;                          // [4096,4096] fp32
  unsigned short* AO   = (unsigned short*)big;                 // reuse: [4096,2048] bf16
  float* of            = (float*)(big + (size_t)cM * cNqkv * 2); // reuse: [4096,2048] fp32

  detect_dtype<<<1, 256, 0, stream>>>((const unsigned*)d_in[0], flag);

  conv_x<<<(cM * cD / 8 + 255) / 256, 256, 0, stream>>>(d_in[0], xb, cM * cD, flag);
  conv_f32<<<(cS * cHD + 255) / 256, 256, 0, stream>>>(d_in[11], cosf_, cS * cHD, flag);
  conv_f32<<<(cS * cHD + 255) / 256, 256, 0, stream>>>(d_in[12], sinf_, cS * cHD, flag);
  conv_f32<<<1, 256, 0, stream>>>(d_in[9], nw, cHD, flag);
  conv_f32<<<1, 256, 0, stream>>>(d_in[10], nw + cHD, cHD, flag);
  conv_f32<<<8, 256, 0, stream>>>(d_in[2], scat, 2048, flag);
  conv_f32<<<4, 256, 0, stream>>>(d_in[4], scat + 2048, 1024, flag);
  conv_f32<<<4, 256, 0, stream>>>(d_in[6], scat + 3072, 1024, flag);
  conv_f32<<<8, 256, 0, stream>>>(d_in[8], so, 2048, flag);
  conv_w<<<(2048 * 2048 / 4 + 255) / 256, 256, 0, stream>>>((const int*)d_in[1], wcat, 2048 * 2048);
  conv_w<<<(1024 * 2048 / 4 + 255) / 256, 256, 0, stream>>>((const int*)d_in[3], wcat + (size_t)2048 * 2048, 1024 * 2048);
  conv_w<<<(1024 * 2048 / 4 + 255) / 256, 256, 0, stream>>>((const int*)d_in[5], wcat + (size_t)3072 * 2048, 1024 * 2048);
  conv_w<<<(2048 * 2048 / 4 + 255) / 256, 256, 0, stream>>>((const int*)d_in[7], wob, 2048 * 2048);

  // Fused QKV projection: [4096,2048] @ [4096,2048]^T -> [4096,4096]
  gemm_bt<<<dim3(cNqkv / 128, cM / 128), 256, 0, stream>>>(xb, wcat, scat, qkvf, cM, cNqkv, cD);
  rmsrope<<<dim3(cM, cH + cKVH), 64, 0, stream>>>(qkvf, cosf_, sinf_, nw, Qb, Kb);
  vtrans<<<dim3(cS / 64, cKVH * cHD / 64, cB), 256, 0, stream>>>(qkvf, Vt);
  attn<<<dim3(cS / 64, cH, cB), 256, 0, stream>>>(Qb, Kb, Vt, AO);
  // O projection: [4096,2048] @ [2048,2048]^T -> [4096,2048]
  gemm_bt<<<dim3(cD / 128, cM / 128), 256, 0, stream>>>(AO, wob, so, of, cM, cD, cH * cHD);
  out_conv<<<(cM * cD + 255) / 256, 256, 0, stream>>>(of, d_out, cM * cD, flag);
}

// Round 2
// 552.416 us; speedup vs baseline: 1.4447x; 1.4447x over previous
//
#include <hip/hip_runtime.h>

// ---------------------------------------------------------------------------
// QuantizedAttention: x[B,S,D] -> QKV proj (int8-quant wts) -> RMSNorm -> RoPE
//   -> causal GQA attention -> O proj.  B=2 S=2048 D=2048 H=16 KVH=8 HD=128.
// Strategy: bf16 MFMA GEMMs (weights exact in bf16, scales applied fp32 in
// epilogue), flash-style attention with online softmax.
// R2: attn rewritten — block-shared LDS K/V tiles (64-kv steps), exp2 softmax.
// Host float-storage dtype (fp32 vs packed bf16) detected on-device.
// ---------------------------------------------------------------------------

typedef __attribute__((ext_vector_type(4))) float floatx4;
typedef __attribute__((ext_vector_type(8))) short short8v;
typedef __attribute__((ext_vector_type(8))) unsigned short ushort8v;
typedef __attribute__((ext_vector_type(4))) unsigned short ushort4v;

#define DEVINL __device__ __forceinline__

constexpr int cB = 2, cS = 2048, cD = 2048, cH = 16, cKVH = 8, cHD = 128;
constexpr int cM = cB * cS;                      // 4096 token rows
constexpr int cNqkv = (cH + 2 * cKVH) * cHD;     // 4096 fused QKV out features
constexpr float cEPS = 1e-6f;
// 1/sqrt(HD) * log2(e): softmax computed in base-2 domain (invariant under
// softmax since all logits share the log2e factor).
constexpr float cSCL2 = 0.08838834764831845f * 1.4426950408889634f;

DEVINL unsigned short f2bf(float f) {            // RNE f32 -> bf16
  unsigned u = __float_as_uint(f);
  unsigned r = ((u >> 16) & 1u) + 0x7FFFu;
  return (unsigned short)((u + r) >> 16);
}
DEVINL float bf2f(unsigned short h) { return __uint_as_float(((unsigned)h) << 16); }

DEVINL floatx4 mfma_bf16(short8v a, short8v b, floatx4 c) {
  return __builtin_amdgcn_mfma_f32_16x16x32_bf16(a, b, c, 0, 0, 0);
}

// --------------------------- dtype detection -------------------------------
__global__ void detect_dtype(const unsigned* __restrict__ x, int* __restrict__ flag) {
  __shared__ int cnt;
  if (threadIdx.x == 0) cnt = 0;
  __syncthreads();
  int c = 0;
  for (int i = threadIdx.x; i < 4096; i += 256) {
    unsigned e = (x[i] >> 7) & 0xFFu;
    c += (e >= 100u && e <= 142u) ? 1 : 0;
  }
  atomicAdd(&cnt, c);
  __syncthreads();
  if (threadIdx.x == 0) *flag = (cnt > 2457) ? 1 : 0;  // 1 = host is bf16
}

// --------------------------- conversions -----------------------------------
__global__ void conv_x(const void* __restrict__ src, unsigned short* __restrict__ dst,
                       int n, const int* __restrict__ flag) {
  int i = (blockIdx.x * 256 + threadIdx.x) * 8;
  if (i >= n) return;
  if (*flag) {
    *(ushort8v*)(dst + i) = *(const ushort8v*)((const unsigned short*)src + i);
  } else {
    const float* s = (const float*)src;
    ushort8v o;
#pragma unroll
    for (int j = 0; j < 8; j++) o[j] = f2bf(s[i + j]);
    *(ushort8v*)(dst + i) = o;
  }
}

__global__ void conv_f32(const void* __restrict__ src, float* __restrict__ dst,
                         int n, const int* __restrict__ flag) {
  int i = blockIdx.x * 256 + threadIdx.x;
  if (i >= n) return;
  dst[i] = (*flag) ? bf2f(((const unsigned short*)src)[i]) : ((const float*)src)[i];
}

__global__ void conv_w(const int* __restrict__ w, unsigned short* __restrict__ dst, int n) {
  int i = (blockIdx.x * 256 + threadIdx.x) * 4;
  if (i >= n) return;
  int4 v = *(const int4*)(w + i);
  ushort4v o;
  o[0] = f2bf((float)v.x); o[1] = f2bf((float)v.y);
  o[2] = f2bf((float)v.z); o[3] = f2bf((float)v.w);
  *(ushort4v*)(dst + i) = o;
}

__global__ void out_conv(const float* __restrict__ of, void* __restrict__ dout,
                         int n, const int* __restrict__ flag) {
  int i = blockIdx.x * 256 + threadIdx.x;
  if (i >= n) return;
  float v = of[i];
  if (*flag) ((unsigned short*)dout)[i] = f2bf(v);
  else       ((float*)dout)[i] = v;
}

// --------------------------- bf16 GEMM (B^T) -------------------------------
__global__ __launch_bounds__(256) void gemm_bt(
    const unsigned short* __restrict__ A, const unsigned short* __restrict__ Bw,
    const float* __restrict__ colscale, float* __restrict__ C,
    int M, int N, int K) {
  constexpr int BK = 64, LDT = BK + 8;
  __shared__ unsigned short As[128 * LDT];
  __shared__ unsigned short Bs[128 * LDT];
  const int tid = threadIdx.x;
  const int lane = tid & 63, wave = tid >> 6;
  const int q = lane >> 4, l16 = lane & 15;
  const int m0 = blockIdx.y * 128, n0 = blockIdx.x * 128;
  const int wm = (wave & 1) * 64, wn = (wave >> 1) * 64;

  floatx4 acc[4][4] = {};

  const int srow = tid >> 1, scol = (tid & 1) * 32;
  const unsigned short* Ag = A + (size_t)(m0 + srow) * K + scol;
  const unsigned short* Bg = Bw + (size_t)(n0 + srow) * K + scol;
  unsigned short* Asw = As + srow * LDT + scol;
  unsigned short* Bsw = Bs + srow * LDT + scol;

  for (int k0 = 0; k0 < K; k0 += BK) {
    ushort8v a0 = *(const ushort8v*)(Ag + k0 + 0);
    ushort8v a1 = *(const ushort8v*)(Ag + k0 + 8);
    ushort8v a2 = *(const ushort8v*)(Ag + k0 + 16);
    ushort8v a3 = *(const ushort8v*)(Ag + k0 + 24);
    ushort8v b0 = *(const ushort8v*)(Bg + k0 + 0);
    ushort8v b1 = *(const ushort8v*)(Bg + k0 + 8);
    ushort8v b2 = *(const ushort8v*)(Bg + k0 + 16);
    ushort8v b3 = *(const ushort8v*)(Bg + k0 + 24);
    __syncthreads();
    *(ushort8v*)(Asw + 0)  = a0;
    *(ushort8v*)(Asw + 8)  = a1;
    *(ushort8v*)(Asw + 16) = a2;
    *(ushort8v*)(Asw + 24) = a3;
    *(ushort8v*)(Bsw + 0)  = b0;
    *(ushort8v*)(Bsw + 8)  = b1;
    *(ushort8v*)(Bsw + 16) = b2;
    *(ushort8v*)(Bsw + 24) = b3;
    __syncthreads();
#pragma unroll
    for (int kk = 0; kk < BK; kk += 32) {
      short8v af[4], bf[4];
#pragma unroll
      for (int mt = 0; mt < 4; mt++)
        af[mt] = *(const short8v*)(As + (wm + mt * 16 + l16) * LDT + kk + q * 8);
#pragma unroll
      for (int nt = 0; nt < 4; nt++)
        bf[nt] = *(const short8v*)(Bs + (wn + nt * 16 + l16) * LDT + kk + q * 8);
#pragma unroll
      for (int mt = 0; mt < 4; mt++)
#pragma unroll
        for (int nt = 0; nt < 4; nt++)
          acc[mt][nt] = mfma_bf16(af[mt], bf[nt], acc[mt][nt]);
    }
  }
#pragma unroll
  for (int mt = 0; mt < 4; mt++) {
    int r0 = m0 + wm + mt * 16 + q * 4;
#pragma unroll
    for (int nt = 0; nt < 4; nt++) {
      int cn = n0 + wn + nt * 16 + l16;
      float sc = colscale[cn];
#pragma unroll
      for (int rg = 0; rg < 4; rg++)
        C[(size_t)(r0 + rg) * N + cn] = acc[mt][nt][rg] * sc;
    }
  }
}

// --------------------------- RMSNorm + RoPE --------------------------------
__global__ __launch_bounds__(64) void rmsrope(
    const float* __restrict__ QKV, const float* __restrict__ cosc,
    const float* __restrict__ sinc, const float* __restrict__ nw,
    unsigned short* __restrict__ Qb, unsigned short* __restrict__ Kb) {
  const int t = threadIdx.x;
  const int row = blockIdx.x;       // b*S + s
  const int hidx = blockIdx.y;      // 0..H+KVH-1
  const int sidx = row & (cS - 1);
  const int bi = row >> 11;
  const bool isq = hidx < cH;
  const int col = isq ? hidx * cHD : cH * cHD + (hidx - cH) * cHD;
  const float* src = QKV + (size_t)row * cNqkv + col;
  float x1 = src[t], x2 = src[t + 64];
  float ss = x1 * x1 + x2 * x2;
  ss += __shfl_xor(ss, 1);  ss += __shfl_xor(ss, 2);  ss += __shfl_xor(ss, 4);
  ss += __shfl_xor(ss, 8);  ss += __shfl_xor(ss, 16); ss += __shfl_xor(ss, 32);
  float inv = rsqrtf(ss * (1.0f / cHD) + cEPS);
  const float* w = nw + (isq ? 0 : cHD);
  float n1 = x1 * inv * w[t], n2 = x2 * inv * w[t + 64];
  float c1 = cosc[sidx * cHD + t], c2 = cosc[sidx * cHD + t + 64];
  float s1 = sinc[sidx * cHD + t], s2 = sinc[sidx * cHD + t + 64];
  float o1 = n1 * c1 - n2 * s1;   // rotate_half: [x1,x2] -> [-x2, x1]
  float o2 = n2 * c2 + n1 * s2;
  unsigned short* dst = isq
      ? (Qb + ((size_t)(bi * cH + hidx) * cS + sidx) * cHD)
      : (Kb + ((size_t)(bi * cKVH + (hidx - cH)) * cS + sidx) * cHD);
  dst[t] = f2bf(o1);
  dst[t + 64] = f2bf(o2);
}

// --------------------------- V transpose -----------------------------------
__global__ __launch_bounds__(256) void vtrans(const float* __restrict__ QKV,
                                              unsigned short* __restrict__ Vt) {
  __shared__ unsigned short tile[64][72];
  const int t = threadIdx.x;
  const int s0 = blockIdx.x * 64, d0 = blockIdx.y * 64, bi = blockIdx.z;
  {
    const int rr = t >> 2, c0 = (t & 3) * 16;
    const float* src = QKV + (size_t)(bi * cS + s0 + rr) * cNqkv
                       + (cH * cHD + cKVH * cHD) + d0 + c0;
#pragma unroll
    for (int j = 0; j < 16; j += 4) {
      float4 v = *(const float4*)(src + j);
      tile[rr][c0 + j + 0] = f2bf(v.x);
      tile[rr][c0 + j + 1] = f2bf(v.y);
      tile[rr][c0 + j + 2] = f2bf(v.z);
      tile[rr][c0 + j + 3] = f2bf(v.w);
    }
  }
  __syncthreads();
  {
    const int dd = t >> 2, sc0 = (t & 3) * 16;
    const int dglob = d0 + dd;
    const int kh = dglob >> 7, dh = dglob & 127;
    unsigned short* dst = Vt + ((size_t)(bi * cKVH + kh) * cHD + dh) * cS + s0 + sc0;
    ushort8v o0, o1;
#pragma unroll
    for (int j = 0; j < 8; j++) { o0[j] = tile[sc0 + j][dd]; o1[j] = tile[sc0 + 8 + j][dd]; }
    *(ushort8v*)dst = o0;
    *(ushort8v*)(dst + 8) = o1;
  }
}

// --------------------------- flash attention (v2) --------------------------
// Block = 64 q-rows of one (b,h); 4 waves, one wave per 16 q-rows.
// Per iter: stage K[64x128] and V[128x64] tiles in LDS (all waves share),
// 16 QK^T MFMAs + exp2-domain online softmax + 16 PV MFMAs per wave.
// LDS padding +8 bf16 -> every fragment read is 2-way bank aliasing (free).
__global__ __launch_bounds__(256, 3) void attn(
    const unsigned short* __restrict__ Qb, const unsigned short* __restrict__ Kb,
    const unsigned short* __restrict__ Vt, unsigned short* __restrict__ AO) {
  constexpr int KLD = 136;  // 128 + 8
  constexpr int VLD = 72;   // 64 + 8
  __shared__ unsigned short Ks[64 * KLD];   // K tile [kv][hd]
  __shared__ unsigned short Vs[128 * VLD];  // V tile [hd][kv]
  __shared__ unsigned short Pl[4][16 * 72]; // wave-private P (A-layout feed)
  const int tid = threadIdx.x;
  const int lane = tid & 63, wv = tid >> 6;
  const int q = lane >> 4, l16 = lane & 15;
  const int bi = blockIdx.z, h = blockIdx.y;
  const int kh = h >> 1;                    // rep = H/KVH = 2
  const int bq0 = blockIdx.x * 64;
  const int q0 = bq0 + wv * 16;             // this wave's first q row

  const unsigned short* Qbase = Qb + ((size_t)(bi * cH + h) * cS + q0) * cHD;
  const unsigned short* Kbase = Kb + ((size_t)(bi * cKVH + kh) * cS) * cHD;
  const unsigned short* Vbase = Vt + ((size_t)(bi * cKVH + kh) * cHD) * cS;

  short8v qa[4];
#pragma unroll
  for (int c = 0; c < 4; c++)
    qa[c] = *(const short8v*)(Qbase + (size_t)l16 * cHD + c * 32 + q * 8);

  floatx4 oacc[8] = {};
  float m_r[4] = {-INFINITY, -INFINITY, -INFINITY, -INFINITY};
  float l_r[4] = {0.f, 0.f, 0.f, 0.f};

  // staging addresses (per thread, 64B each for K and V)
  const int krow = tid >> 2, kc0 = (tid & 3) * 32;
  const int vrow = tid >> 1, vc0 = (tid & 1) * 32;
  const unsigned short* Kg = Kbase + (size_t)krow * cHD + kc0;
  const unsigned short* Vg = Vbase + (size_t)vrow * cS + vc0;
  unsigned short* Ksw = Ks + krow * KLD + kc0;
  unsigned short* Vsw = Vs + vrow * VLD + vc0;

  const int kvend = bq0 + 64;
  for (int kv0 = 0; kv0 < kvend; kv0 += 64) {
    // ---- stage K/V tiles (all 256 threads, coalesced 64B each) ----
    ushort8v k0v = *(const ushort8v*)(Kg + (size_t)kv0 * cHD + 0);
    ushort8v k1v = *(const ushort8v*)(Kg + (size_t)kv0 * cHD + 8);
    ushort8v k2v = *(const ushort8v*)(Kg + (size_t)kv0 * cHD + 16);
    ushort8v k3v = *(const ushort8v*)(Kg + (size_t)kv0 * cHD + 24);
    ushort8v v0v = *(const ushort8v*)(Vg + kv0 + 0);
    ushort8v v1v = *(const ushort8v*)(Vg + kv0 + 8);
    ushort8v v2v = *(const ushort8v*)(Vg + kv0 + 16);
    ushort8v v3v = *(const ushort8v*)(Vg + kv0 + 24);
    __syncthreads();  // previous iter's LDS reads done before overwrite
    *(ushort8v*)(Ksw + 0)  = k0v;
    *(ushort8v*)(Ksw + 8)  = k1v;
    *(ushort8v*)(Ksw + 16) = k2v;
    *(ushort8v*)(Ksw + 24) = k3v;
    *(ushort8v*)(Vsw + 0)  = v0v;
    *(ushort8v*)(Vsw + 8)  = v1v;
    *(ushort8v*)(Vsw + 16) = v2v;
    *(ushort8v*)(Vsw + 24) = v3v;
    __syncthreads();

    if (kv0 <= q0 + 15) {   // wave-uniform: this wave has unmasked columns
      // ---- QK^T: 16 MFMAs -> S[16 q x 64 kv] ----
      floatx4 sres[4] = {};
#pragma unroll
      for (int c = 0; c < 4; c++) {
        short8v kf[4];
#pragma unroll
        for (int nt = 0; nt < 4; nt++)
          kf[nt] = *(const short8v*)(Ks + (nt * 16 + l16) * KLD + c * 32 + q * 8);
#pragma unroll
        for (int nt = 0; nt < 4; nt++)
          sres[nt] = mfma_bf16(qa[c], kf[nt], sres[nt]);
      }
      // ---- mask + scale (log2 domain) ----
      float pm[4][4];  // [nt][rg]
#pragma unroll
      for (int nt = 0; nt < 4; nt++) {
        int colb = kv0 + nt * 16 + l16;
#pragma unroll
        for (int rg = 0; rg < 4; rg++) {
          int row = q0 + q * 4 + rg;
          pm[nt][rg] = (colb <= row) ? sres[nt][rg] * cSCL2 : -INFINITY;
        }
      }
      // ---- online softmax (4 independent rg chains) ----
      float alpha[4];
#pragma unroll
      for (int rg = 0; rg < 4; rg++) {
        float mx = fmaxf(fmaxf(pm[0][rg], pm[1][rg]), fmaxf(pm[2][rg], pm[3][rg]));
        mx = fmaxf(mx, __shfl_xor(mx, 1));
        mx = fmaxf(mx, __shfl_xor(mx, 2));
        mx = fmaxf(mx, __shfl_xor(mx, 4));
        mx = fmaxf(mx, __shfl_xor(mx, 8));
        float mnew = fmaxf(m_r[rg], mx);
        float a = exp2f(m_r[rg] - mnew);   // first iter: exp2(-inf)=0
        float ps = 0.f;
#pragma unroll
        for (int nt = 0; nt < 4; nt++) {
          float p = exp2f(pm[nt][rg] - mnew);
          pm[nt][rg] = p;
          ps += p;
        }
        ps += __shfl_xor(ps, 1);
        ps += __shfl_xor(ps, 2);
        ps += __shfl_xor(ps, 4);
        ps += __shfl_xor(ps, 8);
        l_r[rg] = l_r[rg] * a + ps;
        m_r[rg] = mnew;
        alpha[rg] = a;
      }
      // ---- rescale O accumulator ----
#pragma unroll
      for (int db = 0; db < 8; db++) {
        floatx4 o = oacc[db];
        o[0] *= alpha[0]; o[1] *= alpha[1]; o[2] *= alpha[2]; o[3] *= alpha[3];
        oacc[db] = o;
      }
      // ---- P: C-layout -> wave-private LDS -> A-layout ----
      unsigned short* pw = &Pl[wv][0];
#pragma unroll
      for (int nt = 0; nt < 4; nt++)
#pragma unroll
        for (int rg = 0; rg < 4; rg++)
          pw[(q * 4 + rg) * 72 + nt * 16 + l16] = f2bf(pm[nt][rg]);
      // same-wave LDS ops are ordered; no barrier needed (wave-private)
      // ---- PV: 16 MFMAs ----
#pragma unroll
      for (int kk2 = 0; kk2 < 2; kk2++) {
        short8v pa = *(const short8v*)(pw + l16 * 72 + kk2 * 32 + q * 8);
#pragma unroll
        for (int db = 0; db < 8; db++) {
          short8v vb = *(const short8v*)(Vs + (db * 16 + l16) * VLD + kk2 * 32 + q * 8);
          oacc[db] = mfma_bf16(pa, vb, oacc[db]);
        }
      }
    }
  }
  // ---- epilogue ----
#pragma unroll
  for (int rg = 0; rg < 4; rg++) {
    float inv = 1.0f / l_r[rg];
    int row = q0 + q * 4 + rg;
    unsigned short* dst = AO + (size_t)(bi * cS + row) * (cH * cHD) + h * cHD;
#pragma unroll
    for (int db = 0; db < 8; db++)
      dst[db * 16 + l16] = f2bf(oacc[db][rg] * inv);
  }
}

// --------------------------- launch ----------------------------------------
extern "C" void kernel_launch(void* const* d_in, const int* in_sizes, int n_in,
                              void* d_out, int out_size, void* d_ws, size_t ws_size,
                              hipStream_t stream) {
  (void)in_sizes; (void)n_in; (void)out_size; (void)ws_size;
  char* ws = (char*)d_ws;
  size_t off = 0;
  auto alloc = [&](size_t bytes) -> char* {
    char* p = ws + off;
    off += (bytes + 255) & ~((size_t)255);
    return p;
  };
  int* flag            = (int*)alloc(256);
  float* cosf_         = (float*)alloc((size_t)cS * cHD * 4);
  float* sinf_         = (float*)alloc((size_t)cS * cHD * 4);
  float* nw            = (float*)alloc(256 * 4);               // qw[0:128], kw[128:256]
  float* scat          = (float*)alloc(4096 * 4);              // wq_s|wk_s|wv_s
  float* so            = (float*)alloc(2048 * 4);
  unsigned short* xb   = (unsigned short*)alloc((size_t)cM * cD * 2);
  unsigned short* wcat = (unsigned short*)alloc((size_t)cNqkv * cD * 2);
  unsigned short* wob  = (unsigned short*)alloc((size_t)cD * cH * cHD * 2);
  unsigned short* Qb   = (unsigned short*)alloc((size_t)cB * cH * cS * cHD * 2);
  unsigned short* Kb   = (unsigned short*)alloc((size_t)cB * cKVH * cS * cHD * 2);
  unsigned short* Vt   = (unsigned short*)alloc((size_t)cB * cKVH * cHD * cS * 2);
  char* big            = alloc((size_t)cM * cNqkv * 4);        // 67MB, reused
  float* qkvf          = (float*)big;                          // [4096,4096] fp32
  unsigned short* AO   = (unsigned short*)big;                 // reuse: [4096,2048] bf16
  float* of            = (float*)(big + (size_t)cM * cNqkv * 2); // reuse: [4096,2048] fp32

  detect_dtype<<<1, 256, 0, stream>>>((const unsigned*)d_in[0], flag);

  conv_x<<<(cM * cD / 8 + 255) / 256, 256, 0, stream>>>(d_in[0], xb, cM * cD, flag);
  conv_f32<<<(cS * cHD + 255) / 256, 256, 0, stream>>>(d_in[11], cosf_, cS * cHD, flag);
  conv_f32<<<(cS * cHD + 255) / 256, 256, 0, stream>>>(d_in[12], sinf_, cS * cHD, flag);
  conv_f32<<<1, 256, 0, stream>>>(d_in[9], nw, cHD, flag);
  conv_f32<<<1, 256, 0, stream>>>(d_in[10], nw + cHD, cHD, flag);
  conv_f32<<<8, 256, 0, stream>>>(d_in[2], scat, 2048, flag);
  conv_f32<<<4, 256, 0, stream>>>(d_in[4], scat + 2048, 1024, flag);
  conv_f32<<<4, 256, 0, stream>>>(d_in[6], scat + 3072, 1024, flag);
  conv_f32<<<8, 256, 0, stream>>>(d_in[8], so, 2048, flag);
  conv_w<<<(2048 * 2048 / 4 + 255) / 256, 256, 0, stream>>>((const int*)d_in[1], wcat, 2048 * 2048);
  conv_w<<<(1024 * 2048 / 4 + 255) / 256, 256, 0, stream>>>((const int*)d_in[3], wcat + (size_t)2048 * 2048, 1024 * 2048);
  conv_w<<<(1024 * 2048 / 4 + 255) / 256, 256, 0, stream>>>((const int*)d_in[5], wcat + (size_t)3072 * 2048, 1024 * 2048);
  conv_w<<<(2048 * 2048 / 4 + 255) / 256, 256, 0, stream>>>((const int*)d_in[7], wob, 2048 * 2048);

  // Fused QKV projection: [4096,2048] @ [4096,2048]^T -> [4096,4096]
  gemm_bt<<<dim3(cNqkv / 128, cM / 128), 256, 0, stream>>>(xb, wcat, scat, qkvf, cM, cNqkv, cD);
  rmsrope<<<dim3(cM, cH + cKVH), 64, 0, stream>>>(qkvf, cosf_, sinf_, nw, Qb, Kb);
  vtrans<<<dim3(cS / 64, cKVH * cHD / 64, cB), 256, 0, stream>>>(qkvf, Vt);
  attn<<<dim3(cS / 64, cH, cB), 256, 0, stream>>>(Qb, Kb, Vt, AO);
  // O projection: [4096,2048] @ [2048,2048]^T -> [4096,2048]
  gemm_bt<<<dim3(cD / 128, cM / 128), 256, 0, stream>>>(AO, wob, so, of, cM, cD, cH * cHD);
  out_conv<<<(cM * cD + 255) / 256, 256, 0, stream>>>(of, d_out, cM * cD, flag);
}